// Round 7
// baseline (160.482 us; speedup 1.0000x reference)
//
#include <hip/hip_runtime.h>
#include <math.h>

// Problem constants (B,S,D,V,C) = (32, 2048, 512, 32000, 2)
#define BB   32
#define SS   2048
#define DD   512
#define VV   32000
#define JT   36              // 32 q-rows + w0 + w1 + 2 zero rows
#define QP4  65              // q LDS j-row stride in float4 (64 + 1; ≡1 mod 8)
#define GCH  8               // gather token-chunks per batch

// ---------------------------------------------------------------------------
// Pass 0: QT[36][512] (j-major): row j<32 = emb[tokens[j,0]], 32/33 = cls_w,
// 34/35 = zero. One block per j-row, 128 threads x float4.
// ---------------------------------------------------------------------------
__global__ __launch_bounds__(128) void build_qt(
    const int* __restrict__ tokens, const float* __restrict__ emb,
    const float* __restrict__ cls_w, float* __restrict__ QT)
{
    const int j   = blockIdx.x;    // 0..35
    const int tid = threadIdx.x;   // 128 threads * float4 = 512 floats
    float4 v = make_float4(0.f, 0.f, 0.f, 0.f);
    if (j < 32) {
        const int tok = tokens[(size_t)j * SS];
        v = ((const float4*)(emb + (size_t)tok * DD))[tid];
    } else if (j < 34) {
        v = ((const float4*)(cls_w + (size_t)(j - 32) * DD))[tid];
    }
    ((float4*)QT)[j * (DD / 4) + tid] = v;
}

// ---------------------------------------------------------------------------
// Pass A: Sh[h][v][j] = sum_{d in half h} emb[v][d] * QT[j][d]
// K-split-2 skinny GEMM. Block = 64 rows x 256 dims; grid (500, 2).
// WHY: r5/r6 stalled at 44-50us with all pipe-floors ~8-11us -> latency-bound
// at 2 waves/SIMD (74KB LDS panel). Halving the panel (36.6KB) doubles
// residency: 4 blocks/CU = 4 waves/SIMD.
// Lane = (ks = l&3, jg = (l>>2)&3, rg = l>>4): 4 rows x 9 j x 64 dims/thread;
// per 4-dim chunk: 9 ds_read_b128 (broadcast) feed 144 FMAs.
// K folded IN-WAVE (shfl_xor 1,2 over ks lanes); all 64 lanes store 9 floats.
// Swizzle (verified by enumeration): stride QP4=65 (== 1 mod 8) adds +jg to
// the bank-quad; column map c4 ^ (2*(c4>>4)) adds ^2ks. Quad =
// (jj + jg + (c ^ 2ks)) mod 8 -> each quad serves EXACTLY 2 of the 16
// distinct addresses -> 2-way = free (m136). Same map on stage & read (#21).
// ---------------------------------------------------------------------------
__global__ __launch_bounds__(256, 4) void score_pass(
    const float* __restrict__ emb, const float* __restrict__ QT,
    float* __restrict__ Sh)
{
    const int bx  = blockIdx.x;          // 0..499 row block
    const int h   = blockIdx.y;          // 0..1   K half
    const int tid = threadIdx.x;
    const int w   = tid >> 6;            // wave 0..3
    const int l   = tid & 63;
    const int ks  = l & 3;               // 64-dim subsegment
    const int jg  = (l >> 2) & 3;        // j-group (9 j's)
    const int rg  = l >> 4;              // row group (4 rows)

    __shared__ float4 qs[JT * QP4];      // 36.6 KB -> 4 blocks/CU

    // ---- stage QT[36][cols h*256..+256) -> qs, swizzled (2304 f4 = 9*256)
#pragma unroll
    for (int it = 0; it < 9; ++it) {
        const int idx = it * 256 + tid;
        const int r   = idx >> 6, c4 = idx & 63;
        const int p4  = c4 ^ (2 * (c4 >> 4));          // ^2ks, bits 1-2
        qs[r * QP4 + p4] = ((const float4*)QT)[r * 128 + h * 64 + c4];
    }
    __syncthreads();

    const int row0 = bx * 64 + w * 16 + rg * 4;        // first owned row
    const float* xb = emb + (size_t)row0 * DD + h * 256 + ks * 64;

    float acc[36];                                     // [rr][jj] = acc[rr*9+jj]
#pragma unroll
    for (int k = 0; k < 36; ++k) acc[k] = 0.f;

    float4 xc[4], xn[4];
#pragma unroll
    for (int rr = 0; rr < 4; ++rr)
        xc[rr] = *(const float4*)(xb + rr * DD);

    for (int c = 0; c < 16; ++c) {                     // 16 chunks of 4 dims
        if (c + 1 < 16) {
#pragma unroll
            for (int rr = 0; rr < 4; ++rr)
                xn[rr] = *(const float4*)(xb + rr * DD + (c + 1) * 4);
        }

        const int pc4 = (ks * 16 + c) ^ (2 * ks);      // swizzled phys f4-col
        const float4* qrow = qs + jg * 9 * QP4 + pc4;
#pragma unroll
        for (int jj = 0; jj < 9; ++jj) {
            const float4 q = qrow[jj * QP4];           // broadcast b128
#pragma unroll
            for (int rr = 0; rr < 4; ++rr) {
                float a = acc[rr * 9 + jj];
                a = fmaf(xc[rr].x, q.x, a);
                a = fmaf(xc[rr].y, q.y, a);
                a = fmaf(xc[rr].z, q.z, a);
                a = fmaf(xc[rr].w, q.w, a);
                acc[rr * 9 + jj] = a;
            }
        }

        if (c + 1 < 16) {
#pragma unroll
            for (int rr = 0; rr < 4; ++rr) xc[rr] = xn[rr];
        }
    }

    // ---- in-wave K-reduction: butterfly over ks (lane bits 0..1)
#pragma unroll
    for (int off = 1; off < 4; off <<= 1)
#pragma unroll
        for (int k = 0; k < 36; ++k)
            acc[k] += __shfl_xor(acc[k], off);

    // ---- all lanes store: lane ks takes row row0+ks (acc[ks][.]), 9 floats
    float* dst = Sh + (size_t)h * VV * JT + (size_t)(row0 + ks) * JT + jg * 9;
#pragma unroll
    for (int jj = 0; jj < 9; ++jj) dst[jj] = acc[ks * 9 + jj];
}

// ---------------------------------------------------------------------------
// Pass B: per (batch, 256-token chunk): sum the 2 K-half planes of {s,u,v}
// per token (Sh = 9.2 MB, L2-hot), exp-sum -> one {L,d0,d1} partial.
// ---------------------------------------------------------------------------
__global__ __launch_bounds__(256) void gather_pass(
    const int* __restrict__ tokens, const float* __restrict__ Sh,
    float4* __restrict__ part)
{
    const int b     = blockIdx.x;
    const int chunk = blockIdx.y;
    const int tid   = threadIdx.x;

    const int tok = tokens[(size_t)b * SS + chunk * 256 + tid];
    const float* p0 = Sh + (size_t)tok * JT;
    const float* p1 = p0 + (size_t)VV * JT;

    const float s   = p0[b] + p1[b];                     // q_b . x_t
    const float2 a0 = *(const float2*)(p0 + 32);
    const float2 a1 = *(const float2*)(p1 + 32);
    const float u = a0.x + a1.x, v = a0.y + a1.y;        // w0.x_t, w1.x_t
    const float pe = __expf(s);                          // |s| <~ 0.5
    float L = pe, d0 = pe * u, d1 = pe * v;

#pragma unroll
    for (int off = 32; off > 0; off >>= 1) {
        L  += __shfl_xor(L,  off);
        d0 += __shfl_xor(d0, off);
        d1 += __shfl_xor(d1, off);
    }

    __shared__ float sL[4], s0[4], s1[4];
    const int wave = tid >> 6, lane = tid & 63;
    if (lane == 0) { sL[wave] = L; s0[wave] = d0; s1[wave] = d1; }
    __syncthreads();
    if (tid == 0) {
        part[(size_t)b * GCH + chunk] =
            make_float4(sL[0] + sL[1] + sL[2] + sL[3],
                        s0[0] + s0[1] + s0[2] + s0[3],
                        s1[0] + s1[1] + s1[2] + s1[3], 0.f);
    }
}

// ---------------------------------------------------------------------------
// Pass C: fold the 8 chunk-partials per batch; emit logits. One tiny block.
// ---------------------------------------------------------------------------
__global__ __launch_bounds__(256) void final_merge(
    const float4* __restrict__ part, const float* __restrict__ cls_b,
    float* __restrict__ out)
{
    const int tid = threadIdx.x;       // 256 = 32 b x 8 chunks
    const int b = tid >> 3, i = tid & 7;
    const float4 v = part[b * GCH + i];
    float L = v.x, d0 = v.y, d1 = v.z;
#pragma unroll
    for (int off = 4; off > 0; off >>= 1) {   // 8-lane groups, wave-aligned
        L  += __shfl_xor(L,  off);
        d0 += __shfl_xor(d0, off);
        d1 += __shfl_xor(d1, off);
    }
    if (i == 0) {
        const float inv = 1.0f / L;
        out[b * 2 + 0] = d0 * inv + cls_b[0];
        out[b * 2 + 1] = d1 * inv + cls_b[1];
    }
}

// ---------------------------------------------------------------------------
extern "C" void kernel_launch(void* const* d_in, const int* in_sizes, int n_in,
                              void* d_out, int out_size, void* d_ws, size_t ws_size,
                              hipStream_t stream)
{
    const int*   tokens = (const int*)  d_in[0];   // (32, 2048)
    const float* emb    = (const float*)d_in[1];   // (32000, 512)
    const float* cls_w  = (const float*)d_in[2];   // (2, 512)
    const float* cls_b  = (const float*)d_in[3];   // (2,)
    float*       out    = (float*)d_out;           // (32, 2)

    // Workspace:
    //   QT[36][512]          =  73.7 KB  (j-major)
    //   Sh[2][32000][36]     =   9.2 MB  (two K-half planes, written once)
    //   part[32][8] float4   =   2.0 KB
    float*  QT   = (float*)d_ws;
    float*  Sh   = QT + (size_t)JT * DD;
    float4* part = (float4*)(Sh + (size_t)2 * VV * JT);

    build_qt   <<<JT, 128, 0, stream>>>(tokens, emb, cls_w, QT);
    score_pass <<<dim3(VV / 64, 2), 256, 0, stream>>>(emb, QT, Sh);
    gather_pass<<<dim3(BB, GCH), 256, 0, stream>>>(tokens, Sh, part);
    final_merge<<<1, 256, 0, stream>>>(part, cls_b, out);
}